// Round 11
// baseline (134.461 us; speedup 1.0000x reference)
//
#include <hip/hip_runtime.h>

#define HD 64       // HIDDEN_DIM
#define NE 512      // N_EMBEDS
#define HW 1024     // 32*32 spatial positions per batch image

typedef float f32x2  __attribute__((ext_vector_type(2)));
typedef float f32x4  __attribute__((ext_vector_type(4)));
typedef float f32x16 __attribute__((ext_vector_type(16)));

// ---------------------------------------------------------------------------
// Prep (130 blocks x 256):
//  blk 0..127 : epT[c][k] = -2 * e[k][c]   (transposed, code-major rows)
//  blk 128/129: esq[k] = np.sum(e[k]*e[k]), numpy pairwise-8, no contraction.
//  Verified absmax==0.0 R1-R20.
// ---------------------------------------------------------------------------
__global__ __launch_bounds__(256) void vq_prep_kernel(const float* __restrict__ e,
                                                      float* __restrict__ epT,
                                                      float* __restrict__ esq) {
  const int blk = blockIdx.x;
  if (blk < 128) {
    const int t = blk * 256 + threadIdx.x;     // 0..32767
    const int c = t >> 9, k = t & 511;
    epT[t] = -2.0f * e[k * HD + c];
  } else {
    const int k = (blk - 128) * 256 + threadIdx.x;   // 0..511
    const float4* __restrict__ rowv = reinterpret_cast<const float4*>(e + k * HD);
    float row[HD];
    #pragma unroll
    for (int i = 0; i < 16; ++i) {
      const float4 v = rowv[i];
      row[4 * i + 0] = v.x; row[4 * i + 1] = v.y;
      row[4 * i + 2] = v.z; row[4 * i + 3] = v.w;
    }
    float result;
    {
      #pragma clang fp contract(off)
      float r[8];
      #pragma unroll
      for (int j = 0; j < 8; ++j) r[j] = row[j] * row[j];
      #pragma unroll
      for (int i = 8; i < HD; i += 8) {
        #pragma unroll
        for (int j = 0; j < 8; ++j) r[j] = r[j] + row[i + j] * row[i + j];
      }
      result = ((r[0] + r[1]) + (r[2] + r[3])) + ((r[4] + r[5]) + (r[6] + r[7]));
    }
    esq[k] = result;
  }
}

// ---------------------------------------------------------------------------
// Main R21: 1024 blocks x 1024 threads (16 waves). Block = 64 pos x 512 codes,
// wave wq owns 32 codes [32wq, 32wq+32). == R20 with waves_per_eu(8)->(6).
//
// R20 post-mortem: waves_per_eu(8) capped the unified file at 64 regs/lane;
// natural live set is ~80 (R17 measured: 48 non-acc arch + 32 acc). The
// allocator spilled ~16 dwords/thread: WRITE_SIZE 16->71MB, FETCH 9.3->17MB
// (scratch round-trips), VGPR_Count 32. Occupancy DID jump (36->71%) and
// VALUBusy held ~50% -> the TLP mechanism works; the cap was one notch too
// tight. waves_per_eu(6) -> 80-reg granule == natural live set -> no spill,
// 6 waves/SIMD (24/CU): stall cover 6 x 140cy >> ~200cy SMEM wait.
//
// Validated design (R15/R17/R20 bit-exact on HW):
//  - lane = position; x: ONE coalesced global dword per wave-c.
//  - e on the SCALAR pipe: 4x s_load_dwordx16 (two 128B row slices) +
//    lgkmcnt(0) FUSED in one asm block per 2 c's (consumers dataflow-
//    ordered; in-flight values never cross an asm boundary — the R18/R19
//    separate-wait variants corrupted SGPRs via RA copies).
//  - Inner loop: 32 dense v_fmac_f32 (s[e], v[x]) + 2 xsq ops; zero movs,
//    zero LDS, zero barriers.
//
// Bit-exactness: acc[k] = fma(epT_val, x_val, acc[k]) over c ascending
// (IEEE-commutative operand order, chain identical to R15/R17/R20-verified);
// xsq/esq numpy pairwise-8 trees identical (chain j = c mod 8, c ascending
// within chain); distance (xsq+esq[k])+acc[k] association identical;
// within-lane strict < over ascending codes == first-index-wins; cross-wave
// lexicographic (d,idx) merge (ascending wave == ascending code range) ==
// np.argmin first-occurrence semantics. Grid: 1024 blocks = 64 images x 16
// windows (b=blk>>4, win=blk&15) — coverage audited.
// ---------------------------------------------------------------------------
__global__ __launch_bounds__(1024)
__attribute__((amdgpu_waves_per_eu(6)))
void vq_main_kernel(const float* __restrict__ x,
                    const float* __restrict__ epT,
                    const float* __restrict__ esq,
                    const float* __restrict__ e,
                    float* __restrict__ out) {
  __shared__ f32x2 scr[16 * 64];       // 8 KB: per-wave per-pos (d, idx)
  __shared__ int   bcomb[64];

  const int t    = threadIdx.x;
  const int lane = t & 63;                                  // = position
  const int wq   = __builtin_amdgcn_readfirstlane(t >> 6);  // 0..15 code slot

  const int blk = blockIdx.x;          // 1024
  const int b   = blk >> 4;            // image 0..63
  const int win = blk & 15;            // 64-position window 0..15
  const size_t xbase = (size_t)b * (HD * HW) + (size_t)win * 64;

  const float* __restrict__ xw = x + xbase + lane;
  const unsigned long long ebase =
      (unsigned long long)(const void*)epT + (unsigned)wq * 128u;

  float acc[32];                       // -2*cross accumulators (codes)
  #pragma unroll
  for (int k = 0; k < 32; ++k) acc[k] = 0.f;
  float r[8];                          // xsq pairwise-8 chain partials
  #pragma unroll
  for (int j = 0; j < 8; ++j) r[j] = 0.f;

  #pragma unroll 1
  for (int C = 0; C < 64; C += 8) {
    // x for this 8-c block: per-lane coalesced dwords (compiler pipelines)
    float xv[8];
    #pragma unroll
    for (int j = 0; j < 8; ++j) xv[j] = xw[(size_t)(C + j) * HW];

    #pragma unroll
    for (int jj = 0; jj < 4; ++jj) {   // 2 c-rows per fused scalar asm block
      f32x16 ea0, ea1, eb0, eb1;
      const unsigned long long ea =
          ebase + (unsigned)((C + 2 * jj) * (NE * 4));
      asm volatile(
          "s_load_dwordx16 %0, %4, 0\n\t"
          "s_load_dwordx16 %1, %4, 64\n\t"
          "s_load_dwordx16 %2, %4, 0x800\n\t"
          "s_load_dwordx16 %3, %4, 0x840\n\t"
          "s_waitcnt lgkmcnt(0)"
          : "=&s"(ea0), "=&s"(ea1), "=&s"(eb0), "=&s"(eb1)
          : "s"(ea));

      {  // c = C + 2jj
        const float xc = xv[2 * jj];
        {
          #pragma clang fp contract(off)
          const float sq = xc * xc;
          r[2 * jj] = r[2 * jj] + sq;
        }
        #pragma unroll
        for (int k = 0; k < 16; ++k)
          acc[k] = __builtin_fmaf(ea0[k], xc, acc[k]);
        #pragma unroll
        for (int k = 0; k < 16; ++k)
          acc[16 + k] = __builtin_fmaf(ea1[k], xc, acc[16 + k]);
      }
      {  // c = C + 2jj + 1
        const float xc = xv[2 * jj + 1];
        {
          #pragma clang fp contract(off)
          const float sq = xc * xc;
          r[2 * jj + 1] = r[2 * jj + 1] + sq;
        }
        #pragma unroll
        for (int k = 0; k < 16; ++k)
          acc[k] = __builtin_fmaf(eb0[k], xc, acc[k]);
        #pragma unroll
        for (int k = 0; k < 16; ++k)
          acc[16 + k] = __builtin_fmaf(eb1[k], xc, acc[16 + k]);
      }
    }
  }

  // ---- xsq finish: numpy pairwise-8 tree (contract off), per lane
  float xsql;
  {
    #pragma clang fp contract(off)
    xsql = ((r[0] + r[1]) + (r[2] + r[3])) + ((r[4] + r[5]) + (r[6] + r[7]));
  }

  // ---- esq slice for this wave's 32 codes (scalar pipe, fused pattern)
  f32x16 q0, q1;
  {
    const unsigned long long qa =
        (unsigned long long)(const void*)esq + (unsigned)wq * 128u;
    asm volatile(
        "s_load_dwordx16 %0, %2, 0\n\t"
        "s_load_dwordx16 %1, %2, 64\n\t"
        "s_waitcnt lgkmcnt(0)"
        : "=&s"(q0), "=&s"(q1)
        : "s"(qa));
  }

  // ---- per-lane argmin over the wave's 32 codes (ascending: first-wins)
  float bd = __builtin_inff();
  int   bi = 0x7fffffff;
  const int kb = wq * 32;
  #pragma unroll
  for (int k = 0; k < 16; ++k) {
    const float d = (xsql + q0[k]) + acc[k];
    if (d < bd) { bd = d; bi = kb + k; }
  }
  #pragma unroll
  for (int k = 0; k < 16; ++k) {
    const float d = (xsql + q1[k]) + acc[16 + k];
    if (d < bd) { bd = d; bi = kb + 16 + k; }
  }

  scr[wq * 64 + lane] = (f32x2){bd, __int_as_float(bi)};
  __syncthreads();

  // ---- cross-wave merge: ascending wave == ascending code ranges;
  //      lexicographic (d, idx) == np.argmin first-occurrence.
  if (t < 64) {
    f32x2 p = scr[t];
    float bd2 = p[0];
    int   bi2 = __float_as_int(p[1]);
    #pragma unroll
    for (int w2 = 1; w2 < 16; ++w2) {
      const f32x2 pr = scr[w2 * 64 + t];
      const float d = pr[0];
      const int  ix = __float_as_int(pr[1]);
      if (d < bd2 || (d == bd2 && ix < bi2)) { bd2 = d; bi2 = ix; }
    }
    bcomb[t] = bi2;
  }
  __syncthreads();

  // ---- gather winning codebook rows (L2-hot), coalesced stores
  {
    const int pos = t & 63, cg = t >> 6;      // cg 0..15 -> 4 c's each
    const int idx = bcomb[pos];
    const f32x4 ev = *reinterpret_cast<const f32x4*>(e + idx * HD + cg * 4);
    #pragma unroll
    for (int i = 0; i < 4; ++i)
      out[xbase + (size_t)(cg * 4 + i) * HW + pos] = ev[i];
  }
}

extern "C" void kernel_launch(void* const* d_in, const int* in_sizes, int n_in,
                              void* d_out, int out_size, void* d_ws, size_t ws_size,
                              hipStream_t stream) {
  const float* x = (const float*)d_in[0];   // (64, 64, 32, 32) fp32
  const float* e = (const float*)d_in[1];   // (512, 64) fp32
  float* epT = (float*)d_ws;                // 64*512 floats: -2*e transposed
  float* esq = epT + HD * NE;               // 512 floats
  float* out = (float*)d_out;

  vq_prep_kernel<<<130, 256, 0, stream>>>(e, epT, esq);
  vq_main_kernel<<<1024, 1024, 0, stream>>>(x, epT, esq, e, out);
}

// Round 12
// 131.097 us; speedup vs baseline: 1.0257x; 1.0257x over previous
//
#include <hip/hip_runtime.h>

#define HD 64       // HIDDEN_DIM
#define NE 512      // N_EMBEDS
#define HW 1024     // 32*32 spatial positions per batch image

typedef float f32x2  __attribute__((ext_vector_type(2)));
typedef float f32x4  __attribute__((ext_vector_type(4)));

// ---------------------------------------------------------------------------
// Prep (130 blocks x 256):
//  blk 0..127 : epT[c][k] = -2 * e[k][c]   (transposed, code-major rows)
//  blk 128/129: esq[k] = np.sum(e[k]*e[k]), numpy pairwise-8, no contraction.
//  Verified absmax==0.0 R1-R21.
// ---------------------------------------------------------------------------
__global__ __launch_bounds__(256) void vq_prep_kernel(const float* __restrict__ e,
                                                      float* __restrict__ epT,
                                                      float* __restrict__ esq) {
  const int blk = blockIdx.x;
  if (blk < 128) {
    const int t = blk * 256 + threadIdx.x;     // 0..32767
    const int c = t >> 9, k = t & 511;
    epT[t] = -2.0f * e[k * HD + c];
  } else {
    const int k = (blk - 128) * 256 + threadIdx.x;   // 0..511
    const float4* __restrict__ rowv = reinterpret_cast<const float4*>(e + k * HD);
    float row[HD];
    #pragma unroll
    for (int i = 0; i < 16; ++i) {
      const float4 v = rowv[i];
      row[4 * i + 0] = v.x; row[4 * i + 1] = v.y;
      row[4 * i + 2] = v.z; row[4 * i + 3] = v.w;
    }
    float result;
    {
      #pragma clang fp contract(off)
      float r[8];
      #pragma unroll
      for (int j = 0; j < 8; ++j) r[j] = row[j] * row[j];
      #pragma unroll
      for (int i = 8; i < HD; i += 8) {
        #pragma unroll
        for (int j = 0; j < 8; ++j) r[j] = r[j] + row[i + j] * row[i + j];
      }
      result = ((r[0] + r[1]) + (r[2] + r[3])) + ((r[4] + r[5]) + (r[6] + r[7]));
    }
    esq[k] = result;
  }
}

// ---------------------------------------------------------------------------
// Main R22: 512 blocks x 1024 threads (16 waves). Block = 128 positions
// (two 64-pos windows, lane covers pos=lane and pos=lane+64) x 512 codes
// (wave wq owns 32 codes [32wq, 32wq+32)).
//
// R17/R20/R21 post-mortem: VALU busy time pinned at 37-40us while stall
// stays ~35-40us at 3, 6, AND 8 waves/SIMD -> not coverable latency but
// scalar-memory serialization per CU (every wave's 8KB epT slice streams
// through K$ as all-miss; 16 waves queue on one scalar unit). R22:
//  (1) amortize each e-load over 2 position-windows: 64 fmacs per wave-c
//      per 32-value e-row (compute/wait ratio 2x) and per-CU epT line
//      traffic HALVED (2 blocks/CU x 1024 lines vs 4 x 1024).
//  (2) ZERO inline asm: e loaded via plain C++ uniform loads (address
//      uniform via readfirstlane) -> compiler promotes/batches with its
//      own waitcnt placement; R18/R19 asm hazard class gone by design.
//
// Bit-exactness: acc[k] = fma(epT_val, x_val, acc[k]) over c ascending
// (IEEE-commutative operand order, chain identical to R15/R17/R20/R21-
// verified; two windows are independent accumulators); xsq/esq numpy
// pairwise-8 trees identical (chain j = c mod 8, ascending c per chain);
// distance (xsq+esq[k])+acc[k] association identical; within-lane strict <
// over ascending codes == first-index-wins; cross-wave lexicographic
// (d,idx) merge (ascending wave == ascending code range) == np.argmin
// first-occurrence. Grid: 512 blocks = 64 images x 8 windows x 128 pos
// = 65536 positions — coverage audited (b=blk>>3, win2=blk&7).
// ---------------------------------------------------------------------------
__global__ __launch_bounds__(1024)
void vq_main_kernel(const float* __restrict__ x,
                    const float* __restrict__ epT,
                    const float* __restrict__ esq,
                    const float* __restrict__ e,
                    float* __restrict__ out) {
  __shared__ f32x2 scr[16 * 128];      // 16 KB: per-wave per-pos (d, idx)
  __shared__ int   bcomb[128];

  const int t    = threadIdx.x;
  const int lane = t & 63;
  const int wq   = __builtin_amdgcn_readfirstlane(t >> 6);  // 0..15 code slot

  const int blk = blockIdx.x;          // 512
  const int b   = blk >> 3;            // image 0..63
  const int win2 = blk & 7;            // 128-position window 0..7
  const size_t xbase = (size_t)b * (HD * HW) + (size_t)win2 * 128;

  const float* __restrict__ xw0 = x + xbase + lane;        // window A pos
  const float* __restrict__ xw1 = x + xbase + 64 + lane;   // window B pos
  const float* __restrict__ er = epT + wq * 32;            // wave's 32-code slice

  float acc0[32], acc1[32];            // -2*cross accumulators per window
  #pragma unroll
  for (int k = 0; k < 32; ++k) { acc0[k] = 0.f; acc1[k] = 0.f; }
  float r0[8], r1[8];                  // xsq pairwise-8 chain partials
  #pragma unroll
  for (int j = 0; j < 8; ++j) { r0[j] = 0.f; r1[j] = 0.f; }

  #pragma unroll 1
  for (int C = 0; C < 64; C += 8) {
    // x for this 8-c block, both windows: per-lane coalesced dwords
    float xv0[8], xv1[8];
    #pragma unroll
    for (int j = 0; j < 8; ++j) {
      xv0[j] = xw0[(size_t)(C + j) * HW];
      xv1[j] = xw1[(size_t)(C + j) * HW];
    }

    #pragma unroll
    for (int cc = 0; cc < 8; ++cc) {
      const int c = C + cc;
      // e row slice (32 floats, wave-uniform address): plain C++ loads —
      // compiler scalar-promotes/batches with its own waitcnt schedule.
      const float* __restrict__ erow = er + (size_t)c * NE;
      float ev[32];
      #pragma unroll
      for (int k = 0; k < 8; ++k) {
        const f32x4 v = *reinterpret_cast<const f32x4*>(erow + 4 * k);
        ev[4 * k + 0] = v[0]; ev[4 * k + 1] = v[1];
        ev[4 * k + 2] = v[2]; ev[4 * k + 3] = v[3];
      }

      const float xc0 = xv0[cc];
      const float xc1 = xv1[cc];
      {
        #pragma clang fp contract(off)
        const float sq0 = xc0 * xc0;
        r0[cc] = r0[cc] + sq0;
        const float sq1 = xc1 * xc1;
        r1[cc] = r1[cc] + sq1;
      }
      #pragma unroll
      for (int k = 0; k < 32; ++k) {
        acc0[k] = __builtin_fmaf(ev[k], xc0, acc0[k]);
        acc1[k] = __builtin_fmaf(ev[k], xc1, acc1[k]);
      }
    }
  }

  // ---- xsq finish: numpy pairwise-8 tree (contract off), per lane/window
  float xsq0, xsq1;
  {
    #pragma clang fp contract(off)
    xsq0 = ((r0[0] + r0[1]) + (r0[2] + r0[3])) + ((r0[4] + r0[5]) + (r0[6] + r0[7]));
    xsq1 = ((r1[0] + r1[1]) + (r1[2] + r1[3])) + ((r1[4] + r1[5]) + (r1[6] + r1[7]));
  }

  // ---- esq slice for this wave's 32 codes (plain C++ uniform loads)
  float qv[32];
  {
    const float* __restrict__ qrow = esq + wq * 32;
    #pragma unroll
    for (int k = 0; k < 8; ++k) {
      const f32x4 v = *reinterpret_cast<const f32x4*>(qrow + 4 * k);
      qv[4 * k + 0] = v[0]; qv[4 * k + 1] = v[1];
      qv[4 * k + 2] = v[2]; qv[4 * k + 3] = v[3];
    }
  }

  // ---- per-lane argmin over the wave's 32 codes (ascending: first-wins)
  float bd0 = __builtin_inff(), bd1 = __builtin_inff();
  int   bi0 = 0x7fffffff,       bi1 = 0x7fffffff;
  const int kb = wq * 32;
  #pragma unroll
  for (int k = 0; k < 32; ++k) {
    const float d0 = (xsq0 + qv[k]) + acc0[k];
    if (d0 < bd0) { bd0 = d0; bi0 = kb + k; }
    const float d1 = (xsq1 + qv[k]) + acc1[k];
    if (d1 < bd1) { bd1 = d1; bi1 = kb + k; }
  }

  scr[wq * 128 + lane]      = (f32x2){bd0, __int_as_float(bi0)};
  scr[wq * 128 + 64 + lane] = (f32x2){bd1, __int_as_float(bi1)};
  __syncthreads();

  // ---- cross-wave merge: ascending wave == ascending code ranges;
  //      lexicographic (d, idx) == np.argmin first-occurrence.
  if (t < 128) {
    f32x2 p = scr[t];
    float bd2 = p[0];
    int   bi2 = __float_as_int(p[1]);
    #pragma unroll
    for (int w2 = 1; w2 < 16; ++w2) {
      const f32x2 pr = scr[w2 * 128 + t];
      const float d = pr[0];
      const int  ix = __float_as_int(pr[1]);
      if (d < bd2 || (d == bd2 && ix < bi2)) { bd2 = d; bi2 = ix; }
    }
    bcomb[t] = bi2;
  }
  __syncthreads();

  // ---- gather winning codebook rows (L2-hot), coalesced stores
  {
    const int pos = t & 127, cg = t >> 7;     // cg 0..7 -> 8 c's each
    const int idx = bcomb[pos];
    const f32x4 ev0 = *reinterpret_cast<const f32x4*>(e + idx * HD + cg * 8);
    const f32x4 ev1 = *reinterpret_cast<const f32x4*>(e + idx * HD + cg * 8 + 4);
    #pragma unroll
    for (int i = 0; i < 4; ++i)
      out[xbase + (size_t)(cg * 8 + i) * HW + pos] = ev0[i];
    #pragma unroll
    for (int i = 0; i < 4; ++i)
      out[xbase + (size_t)(cg * 8 + 4 + i) * HW + pos] = ev1[i];
  }
}

extern "C" void kernel_launch(void* const* d_in, const int* in_sizes, int n_in,
                              void* d_out, int out_size, void* d_ws, size_t ws_size,
                              hipStream_t stream) {
  const float* x = (const float*)d_in[0];   // (64, 64, 32, 32) fp32
  const float* e = (const float*)d_in[1];   // (512, 64) fp32
  float* epT = (float*)d_ws;                // 64*512 floats: -2*e transposed
  float* esq = epT + HD * NE;               // 512 floats
  float* out = (float*)d_out;

  vq_prep_kernel<<<130, 256, 0, stream>>>(e, epT, esq);
  vq_main_kernel<<<512, 1024, 0, stream>>>(x, epT, esq, e, out);
}